// Round 8
// baseline (389.282 us; speedup 1.0000x reference)
//
#include <hip/hip_runtime.h>
#include <stdint.h>

// Problem constants (fixed by setup_inputs; all tensors f32)
#define B_ROWS 4096
#define D_IN   784
#define H_DIM  800
#define D_OUT  10
#define T_SIM  32
#define N_ELEM (B_ROWS * D_IN)   // 3211264
#define CAP    448               // spiking-list cap/row (mean ~376, sd ~14)

// ---------------------------------------------------------------------------
// Bit-exact JAX threefry2x32 (key = PRNGKey(42) = {0, 42})
// ---------------------------------------------------------------------------
__device__ __forceinline__ void threefry2x32(uint32_t k0, uint32_t k1,
                                             uint32_t& x0, uint32_t& x1) {
  uint32_t ks0 = k0, ks1 = k1, ks2 = k0 ^ k1 ^ 0x1BD11BDAu;
  x0 += ks0; x1 += ks1;
#define TF_RND(r) { x0 += x1; x1 = (x1 << (r)) | (x1 >> (32 - (r))); x1 ^= x0; }
  TF_RND(13) TF_RND(15) TF_RND(26) TF_RND(6)
  x0 += ks1; x1 += ks2 + 1u;
  TF_RND(17) TF_RND(29) TF_RND(16) TF_RND(24)
  x0 += ks2; x1 += ks0 + 2u;
  TF_RND(13) TF_RND(15) TF_RND(26) TF_RND(6)
  x0 += ks0; x1 += ks1 + 3u;
  TF_RND(17) TF_RND(29) TF_RND(16) TF_RND(24)
  x0 += ks1; x1 += ks2 + 4u;
  TF_RND(13) TF_RND(15) TF_RND(26) TF_RND(6)
  x0 += ks2; x1 += ks0 + 5u;
#undef TF_RND
}

// ---------------------------------------------------------------------------
// K0a: x_fixed computed DIRECTLY in transposed layout xfT[k][m] (k-major).
// Same threefry counter i = m*784 + k -> bit-identical values.
// ---------------------------------------------------------------------------
__global__ __launch_bounds__(256) void gen_xfixed_T(const float* __restrict__ x,
                                                    float* __restrict__ xfT) {
  const int m = blockIdx.x * 256 + threadIdx.x;   // 0..4095
  const int kb = blockIdx.y * 16;                 // 0,16,..,768
#pragma unroll 1
  for (int kk = 0; kk < 16; ++kk) {
    const int k = kb + kk;
    const int i = m * D_IN + k;
    uint32_t c0 = 0u, c1 = (uint32_t)i;
    threefry2x32(0u, 42u, c0, c1);
    uint32_t bits = c0 ^ c1;
    float u = __uint_as_float((bits >> 9) | 0x3F800000u) - 1.0f;
    xfT[(size_t)k * B_ROWS + m] = (u < x[i]) ? 1.0f : 0.0f;
  }
}

// K0b: W1T[k][h] = W1[h][k] — bit-exact copy, 2.5 MB. Coalesced writes.
__global__ __launch_bounds__(256) void transpose_w1(const float* __restrict__ W1,
                                                    float* __restrict__ W1T) {
  const int idx = blockIdx.x * 256 + threadIdx.x;   // over k*800+h
  if (idx >= D_IN * H_DIM) return;
  const int k = idx / H_DIM;
  const int h = idx - k * H_DIM;
  W1T[idx] = W1[h * D_IN + k];
}

// K0c: W2GT[h*10+o] = W2[o*800+h] — 32 KB, L1/L2-resident gather target.
__global__ __launch_bounds__(256) void transpose_w2(const float* __restrict__ W2,
                                                    float* __restrict__ W2GT) {
  const int idx = blockIdx.x * 256 + threadIdx.x;   // h*10+o
  if (idx >= H_DIM * D_OUT) return;
  const int h = idx / D_OUT;
  const int o = idx - h * D_OUT;
  W2GT[idx] = W2[o * H_DIM + h];
}

// ---------------------------------------------------------------------------
// K1 (R8): R6's proven sync structure (async global_load_lds width-16, LDS
// double-buffer, ONE plain __syncthreads per tile — R7's hand-vmcnt variant
// regressed 144.5->186, compiler schedule wins) with a WIDER tile:
// BM=128 x BN=64, 8x4 per-thread acc.  B/FMA falls 2.0 -> 1.5 ->
// LDS-read floor 126 -> ~94 us (incl. 1.23x block imbalance).  Grid 416
// blocks = 6.5 waves/CU; tolerable only because staging is async+dbuf
// (R2's 183-us failure at this shape was register-staging latency).
// Staging: per wave per tile 3 global_load_lds (A: 2 instr covering 4 rows
// of 128 floats; B: 1 instr covering 4 rows of 64) — linear LDS dest.
// Read conflicts: A-frag 4-distinct broadcast (free), B-frag 2-way (free).
// Exactness: per output single f32 acc, strict ascending-k fma chain,
// identical epilogue -> bit-identical (absmax 0.0).
// ---------------------------------------------------------------------------
#define BK 16

#define GL2LDS(g, l) __builtin_amdgcn_global_load_lds(                      \
    (const __attribute__((address_space(1))) void*)(g),                     \
    (__attribute__((address_space(3))) void*)(l), 16, 0, 0)

__global__ __launch_bounds__(256) void gemm_masks(const float* __restrict__ xfT,
                                                  const float* __restrict__ W1T,
                                                  const float* __restrict__ b1,
                                                  uint32_t* __restrict__ mb) {
  __shared__ __align__(16) float As[2][BK][128];  // 2 x 8 KB, linear
  __shared__ __align__(16) float Bs[2][BK][64];   // 2 x 4 KB, linear
  const int t  = threadIdx.x;        // 0..255
  const int tx = t & 15;             // h-group: 4 cols
  const int ty = t >> 4;             // m-group: 8 rows (0..15)
  const int m0 = blockIdx.y * 128;
  const int n0 = blockIdx.x * 64;

  // staging geometry (wave w, lane l):
  //  A instr j (j=0,1): slab = rows 4w+2j..4w+2j+1 of 16x128 tile (1 KB);
  //    lane l -> row 4w+2j+(l>>5), col (l&31)*4
  //  B: slab = rows 4w..4w+3 of 16x64 tile (1 KB);
  //    lane l -> row 4w+(l>>4), col (l&15)*4
  const int w = t >> 6;              // wave 0..3
  const int l = t & 63;              // lane
  const int skkA0 = 4 * w + 0 + (l >> 5);
  const int skkA1 = 4 * w + 2 + (l >> 5);
  const int smA   = (l & 31) * 4;
  const int skkB  = 4 * w + (l >> 4);
  const int smB   = (l & 15) * 4;
  const float* gA0 = xfT + (size_t)skkA0 * B_ROWS + m0 + smA;  // + tt*16*4096
  const float* gA1 = xfT + (size_t)skkA1 * B_ROWS + m0 + smA;
  const float* gB  = W1T + (size_t)skkB * H_DIM + n0 + smB;    // + tt*16*800

#define STAGE(buf, tt) {                                                    \
    GL2LDS(gA0 + (size_t)(tt) * BK * B_ROWS, &As[buf][4 * w][0]);           \
    GL2LDS(gA1 + (size_t)(tt) * BK * B_ROWS, &As[buf][4 * w + 2][0]);       \
    GL2LDS(gB  + (size_t)(tt) * BK * H_DIM,  &Bs[buf][4 * w][0]); }

  STAGE(0, 0);
  __syncthreads();                       // vmcnt(0) drain -> tile 0 ready

  float acc[8][4] = {};
  const int NT = D_IN / BK;              // 49 tiles, ascending k
#pragma unroll 1
  for (int tt = 0; tt < NT; ++tt) {
    const int cur = tt & 1;
    if (tt + 1 < NT) STAGE(cur ^ 1, tt + 1);   // async into other buffer
#pragma unroll
    for (int kk = 0; kk < BK; kk++) {    // strict ascending k, single acc
      float4 av0 = *(const float4*)&As[cur][kk][ty * 8];      // ds_read_b128
      float4 av1 = *(const float4*)&As[cur][kk][ty * 8 + 4];  // ds_read_b128
      float4 bv  = *(const float4*)&Bs[cur][kk][tx * 4];      // ds_read_b128
      float a[8] = {av0.x, av0.y, av0.z, av0.w, av1.x, av1.y, av1.z, av1.w};
      float b[4] = {bv.x, bv.y, bv.z, bv.w};
#pragma unroll
      for (int mi = 0; mi < 8; mi++)
#pragma unroll
        for (int ni = 0; ni < 4; ni++)
          acc[mi][ni] = __builtin_fmaf(a[mi], b[ni], acc[mi][ni]);
    }
    __syncthreads();                     // ONE barrier per tile (proven R6)
  }
#undef STAGE

  // Epilogue: + b1 (f32 add like ref), exact f32 IF-period loop, emit mask32
  const int hOut = n0 + tx * 4;          // multiple of 4
  if (hOut < H_DIM) {
    float4 bb = *(const float4*)&b1[hOut];
#pragma unroll
    for (int mi = 0; mi < 8; mi++) {
      int m = m0 + ty * 8 + mi;
      float c4[4] = {acc[mi][0] + bb.x, acc[mi][1] + bb.y,
                     acc[mi][2] + bb.z, acc[mi][3] + bb.w};
      uint32_t mk4[4];
#pragma unroll
      for (int ni = 0; ni < 4; ni++) {
        float c = c4[ni];
        float v = 0.0f;
        int p = 0;
#pragma unroll 1
        for (int s = 1; s <= T_SIM; s++) {
          float h1 = v + c;                   // f32 add, as reference
          if (h1 >= 1.0f) { p = s; break; }
          v = h1;
        }
        uint32_t mk = 0;
        if (p) for (int s = p; s <= T_SIM; s += p) mk |= 1u << (s - 1);
        mk4[ni] = mk;
      }
      *(uint4*)&mb[(size_t)m * H_DIM + hOut] =
          make_uint4(mk4[0], mk4[1], mk4[2], mk4[3]);
    }
  }
}

// ---------------------------------------------------------------------------
// K2 (R8): SNN scan — w-gather moved OFF the LDS pipe.  Exec-loop model of
// R6: ~104 us of LDS time (2 ds_read_b64/entry).  Since the entry index i is
// wave-uniform, the w-load address is 2-distinct per wave -> a GLOBAL
// dwordx2 from W2GT (32 KB, L1-resident) is broadcast-class.  Exec is now
// 1 ds_read_b64 (pk) + 1 VMEM (parallel pipe): LDS work halves, and the
// whole W2T-LDS staging phase is deleted.  LDS 40 KB -> ~8 KB ->
// 6 blocks/CU (30 waves, was 20).
// Exactness: identical ascending-h single-accumulator gated fold; w values
// bit-identical (W2GT is a copy); pads (mask=0) add exact +0.0f.
// Overflow (>CAP) -> gated full scan over W2GT, same order.
// ---------------------------------------------------------------------------
__global__ __launch_bounds__(320) void snn_scan(const uint32_t* __restrict__ mb,
                                                const float* __restrict__ W2GT,
                                                const float* __restrict__ b2,
                                                float* __restrict__ out) {
  __shared__ __align__(16) uint2 pkS[2][CAP];         // {h*40, mask}, 7168 B
  __shared__ int   lenS[2];
  __shared__ float b2f[D_OUT];
  float* c2s = (float*)&pkS[0][0];            // union: [r][t][o], 2560 B
  const int tid  = threadIdx.x;               // 0..319
  const int row0 = blockIdx.x * 2;

  if (tid < D_OUT) b2f[tid] = b2[tid];

  if (tid < 128) {
    // ---- Build (waves 0-1): ballot-compact mask words, ascending h ----
    const int r = tid >> 6, ln = tid & 63;
    const uint64_t lm = (1ull << ln) - 1ull;
    const uint32_t* mrow = mb + (size_t)(row0 + r) * H_DIM;
    uint32_t mv[13];
#pragma unroll
    for (int ch = 0; ch < 13; ++ch) {         // independent coalesced loads
      int h = ch * 64 + ln;
      mv[ch] = (h < H_DIM) ? mrow[h] : 0u;
    }
    int off = 0;
#pragma unroll
    for (int ch = 0; ch < 13; ++ch) {
      bool g = (mv[ch] != 0u);
      uint64_t bal = __ballot(g);
      int pos = off + __popcll(bal & lm);
      if (g && pos < CAP) {
        uint2 pk; pk.x = (uint32_t)((ch * 64 + ln) * 40); pk.y = mv[ch];
        pkS[r][pos] = pk;
      }
      off += __popcll(bal);
    }
    if (off <= CAP) {                         // self-pad to multiple of 64
      int lp = (off + 63) & ~63;              // <= CAP since off <= CAP
      int i = off + ln;
      if (i < lp) { pkS[r][i].x = 0u; pkS[r][i].y = 0u; }
    }
    if (ln == 0) lenS[r] = off;
  }
  __syncthreads();

  // ---- Exec: wave j = o-pair, lanes (t, r); 1 LDS + 1 VMEM per entry ----
  float s0 = 0.0f, s1 = 0.0f;
  const int j = tid >> 6;                     // 0..4
  const int lane = tid & 63;
  const int t = lane & 31;
  const int r = lane >> 5;
  const bool ovf = (lenS[0] > CAP) || (lenS[1] > CAP);
  {
    const char* wg = (const char*)W2GT + 8 * j;
    if (!ovf) {
      const int Lpad = (lenS[r] + 63) & ~63;  // per-r trip count (divergent ok)
      const uint2* pp = pkS[r];
#pragma unroll 8
      for (int i = 0; i < Lpad; ++i) {
        uint2 pk = pp[i];                     // b64, 2-distinct broadcast
        float2 w = *(const float2*)(wg + pk.x);  // global, L1-hit, 2-distinct
        bool g = (pk.y >> t) & 1u;
        s0 += g ? w.x : 0.0f;                 // identical op to ref (+w / +0)
        s1 += g ? w.y : 0.0f;
      }
    } else {                                  // overflow fallback: gated scan
      const uint32_t* mrow = mb + (size_t)(row0 + r) * H_DIM;
      const uint32_t vbit = 1u << t;
      for (int h = 0; h < H_DIM; ++h) {
        uint32_t mk = mrow[h];
        float2 w = *(const float2*)(wg + h * 40);
        s0 += (mk & vbit) ? w.x : 0.0f;
        s1 += (mk & vbit) ? w.y : 0.0f;
      }
    }
  }
  __syncthreads();                            // all pk reads complete
  c2s[((r * T_SIM) + t) * D_OUT + 2 * j]     = s0;   // union region write
  c2s[((r * T_SIM) + t) * D_OUT + 2 * j + 1] = s1;
  __syncthreads();

  // ---- Layer-2 IF scan + spike count (exact f32 ref order) ----
  if (tid < 2 * D_OUT) {
    const int rr = tid / D_OUT, o = tid % D_OUT;
    const float bb = b2f[o];
    float v = 0.0f; int cnt = 0;
#pragma unroll
    for (int tt = 0; tt < T_SIM; ++tt) {
      float cur2 = c2s[((rr * T_SIM) + tt) * D_OUT + o] + bb;  // f32 add
      float h2 = v + cur2;                    // f32 add
      bool spk = (h2 >= 1.0f);
      cnt += spk ? 1 : 0;
      v = spk ? 0.0f : h2;
    }
    out[(size_t)(row0 + rr) * D_OUT + o] = (float)cnt;
  }
}

// ---------------------------------------------------------------------------
extern "C" void kernel_launch(void* const* d_in, const int* in_sizes, int n_in,
                              void* d_out, int out_size, void* d_ws, size_t ws_size,
                              hipStream_t stream) {
  const float* x  = (const float*)d_in[0];
  const float* W1 = (const float*)d_in[1];
  const float* b1 = (const float*)d_in[2];
  const float* W2 = (const float*)d_in[3];
  const float* b2 = (const float*)d_in[4];
  float* outp = (float*)d_out;

  float*    xfT  = (float*)d_ws;                    // 784*4096 f32 (12.85 MB)
  float*    W1T  = xfT + (size_t)D_IN * B_ROWS;     // 784*800  f32 ( 2.51 MB)
  float*    W2GT = W1T + (size_t)D_IN * H_DIM;      // 800*10   f32 (32 KB)
  uint32_t* mbuf = (uint32_t*)(W2GT + H_DIM * D_OUT);  // B*H u32 (13.1 MB)

  gen_xfixed_T<<<dim3(16, 49), 256, 0, stream>>>(x, xfT);
  transpose_w1<<<(D_IN * H_DIM + 255) / 256, 256, 0, stream>>>(W1, W1T);
  transpose_w2<<<(H_DIM * D_OUT + 255) / 256, 256, 0, stream>>>(W2, W2GT);

  dim3 g1(13, 32);                                  // 13 x 32 = 416 blocks
  gemm_masks<<<g1, 256, 0, stream>>>(xfT, W1T, b1, mbuf);

  snn_scan<<<B_ROWS / 2, 320, 0, stream>>>(mbuf, W2GT, b2, outp);
}

// Round 9
// 293.189 us; speedup vs baseline: 1.3278x; 1.3278x over previous
//
#include <hip/hip_runtime.h>
#include <stdint.h>

// Problem constants (fixed by setup_inputs; all tensors f32)
#define B_ROWS 4096
#define D_IN   784
#define H_DIM  800
#define D_OUT  10
#define T_SIM  32
#define N_ELEM (B_ROWS * D_IN)   // 3211264
#define CAP    448               // spiking-list cap/row (mean ~376, sd ~14)

// ---------------------------------------------------------------------------
// Bit-exact JAX threefry2x32 (key = PRNGKey(42) = {0, 42})
// ---------------------------------------------------------------------------
__device__ __forceinline__ void threefry2x32(uint32_t k0, uint32_t k1,
                                             uint32_t& x0, uint32_t& x1) {
  uint32_t ks0 = k0, ks1 = k1, ks2 = k0 ^ k1 ^ 0x1BD11BDAu;
  x0 += ks0; x1 += ks1;
#define TF_RND(r) { x0 += x1; x1 = (x1 << (r)) | (x1 >> (32 - (r))); x1 ^= x0; }
  TF_RND(13) TF_RND(15) TF_RND(26) TF_RND(6)
  x0 += ks1; x1 += ks2 + 1u;
  TF_RND(17) TF_RND(29) TF_RND(16) TF_RND(24)
  x0 += ks2; x1 += ks0 + 2u;
  TF_RND(13) TF_RND(15) TF_RND(26) TF_RND(6)
  x0 += ks0; x1 += ks1 + 3u;
  TF_RND(17) TF_RND(29) TF_RND(16) TF_RND(24)
  x0 += ks1; x1 += ks2 + 4u;
  TF_RND(13) TF_RND(15) TF_RND(26) TF_RND(6)
  x0 += ks2; x1 += ks0 + 5u;
#undef TF_RND
}

// ---------------------------------------------------------------------------
// K0a: x_fixed as BYTES in transposed layout xf8[k][m].  Same threefry
// counter i = m*784 + k -> bit-identical spike decisions; u8 1 -> f32 1.0
// conversion in K1 is exact, so downstream arithmetic is bit-identical.
// ---------------------------------------------------------------------------
__global__ __launch_bounds__(256) void gen_xfixed8(const float* __restrict__ x,
                                                   uint8_t* __restrict__ xf8) {
  const int m = blockIdx.x * 256 + threadIdx.x;   // 0..4095
  const int kb = blockIdx.y * 16;                 // 0,16,..,768
#pragma unroll 1
  for (int kk = 0; kk < 16; ++kk) {
    const int k = kb + kk;
    const int i = m * D_IN + k;
    uint32_t c0 = 0u, c1 = (uint32_t)i;
    threefry2x32(0u, 42u, c0, c1);
    uint32_t bits = c0 ^ c1;
    float u = __uint_as_float((bits >> 9) | 0x3F800000u) - 1.0f;
    xf8[(size_t)k * B_ROWS + m] = (u < x[i]) ? (uint8_t)1 : (uint8_t)0;
  }
}

// K0b: W1T[k][h] = W1[h][k] — bit-exact copy, 2.5 MB. Coalesced writes.
__global__ __launch_bounds__(256) void transpose_w1(const float* __restrict__ W1,
                                                    float* __restrict__ W1T) {
  const int idx = blockIdx.x * 256 + threadIdx.x;   // over k*800+h
  if (idx >= D_IN * H_DIM) return;
  const int k = idx / H_DIM;
  const int h = idx - k * H_DIM;
  W1T[idx] = W1[h * D_IN + k];
}

// ---------------------------------------------------------------------------
// K1 (R9): R6's proven structure (64x64/4x4, async global_load_lds, dbuf,
// ONE __syncthreads/tile, 832 blocks = 13 waves/CU) with A stored in LDS as
// u8.  R6 measured 144.5 us = 71% of a 102-us ds_read floor; the floor is
// byte-driven, and binary A cuts the A-fragment read from b128 (12 cyc) to
// a 4-distinct-broadcast b32 (~5.8 cyc): floor -> ~76 us.  A-tile staging
// is ONE global_load_lds (1 KB) by wave 0; B staging unchanged.
// u8->f32 via v_cvt_f32_ubyte{0..3} (4 VALU/thread/kk; VALU stays under
// the LDS floor).  fma(1.0,b,acc)/fma(0.0,b,acc) are the identical ops of
// the f32 kernel -> bit-identical accumulator chain (absmax 0.0).
// LDS 10.2 KB, VGPR ~40.  (128-wide tiles thrice-refuted: R2/R8 = 186 us
// at 1.6 blocks/CU; hand-vmcnt refuted: R7 = 186 us.)
// ---------------------------------------------------------------------------
#define BK 16

#define GL2LDS(g, l) __builtin_amdgcn_global_load_lds(                      \
    (const __attribute__((address_space(1))) void*)(g),                     \
    (__attribute__((address_space(3))) void*)(l), 16, 0, 0)

__global__ __launch_bounds__(256) void gemm_masks(const uint8_t* __restrict__ xf8,
                                                  const float* __restrict__ W1T,
                                                  const float* __restrict__ b1,
                                                  uint32_t* __restrict__ mb) {
  __shared__ __align__(16) uint8_t As8[2][BK][64];  // 2 x 1 KB, linear
  __shared__ __align__(16) float   Bs[2][BK][64];   // 2 x 4 KB, linear
  const int t  = threadIdx.x;        // 0..255
  const int tx = t & 15, ty = t >> 4;
  const int m0 = blockIdx.y * 64;
  const int n0 = blockIdx.x * 64;

  // staging geometry:
  //  A (wave 0 only): whole 16x64-byte tile = 1 instr; lane l -> byte l*16
  //    = row l>>2, col (l&3)*16 of the tile.
  //  B (each wave w): rows 4w..4w+3 of 16x64 f32 tile = 1 instr;
  //    lane l -> row 4w+(l>>4), col (l&15)*4.
  const int w = t >> 6;              // wave 0..3
  const int l = t & 63;              // lane
  const uint8_t* gA = xf8 + (size_t)(l >> 2) * B_ROWS + m0 + (l & 3) * 16;
  const int skkB = 4 * w + (l >> 4);
  const float* gB = W1T + (size_t)skkB * H_DIM + n0 + (l & 15) * 4;

#define STAGE(buf, tt) {                                                    \
    if (w == 0) GL2LDS(gA + (size_t)(tt) * BK * B_ROWS, &As8[buf][0][0]);   \
    GL2LDS(gB + (size_t)(tt) * BK * H_DIM, &Bs[buf][4 * w][0]); }

  STAGE(0, 0);
  __syncthreads();                       // vmcnt(0) drain -> tile 0 ready

  float acc[4][4] = {};
  const int NT = D_IN / BK;              // 49 tiles, ascending k
#pragma unroll 1
  for (int tt = 0; tt < NT; ++tt) {
    const int cur = tt & 1;
    if (tt + 1 < NT) STAGE(cur ^ 1, tt + 1);   // async into other buffer
#pragma unroll
    for (int kk = 0; kk < BK; kk++) {    // strict ascending k, single acc
      uint32_t a4u = *(const uint32_t*)&As8[cur][kk][ty * 4]; // ds_read_b32
      float4 bv = *(const float4*)&Bs[cur][kk][tx * 4];       // ds_read_b128
      float a[4];                         // v_cvt_f32_ubyte0..3 (exact 0/1)
      a[0] = (float)(a4u & 0xffu);
      a[1] = (float)((a4u >> 8) & 0xffu);
      a[2] = (float)((a4u >> 16) & 0xffu);
      a[3] = (float)(a4u >> 24);
      float b[4] = {bv.x, bv.y, bv.z, bv.w};
#pragma unroll
      for (int mi = 0; mi < 4; mi++)
#pragma unroll
        for (int ni = 0; ni < 4; ni++)
          acc[mi][ni] = __builtin_fmaf(a[mi], b[ni], acc[mi][ni]);
    }
    __syncthreads();                     // ONE barrier per tile (proven R6)
  }
#undef STAGE

  // Epilogue: + b1 (f32 add like ref), exact f32 IF-period loop, emit mask32
  const int hOut = n0 + tx * 4;          // multiple of 4
  if (hOut < H_DIM) {
    float4 bb = *(const float4*)&b1[hOut];
#pragma unroll
    for (int mi = 0; mi < 4; mi++) {
      int m = m0 + ty * 4 + mi;
      float c4[4] = {acc[mi][0] + bb.x, acc[mi][1] + bb.y,
                     acc[mi][2] + bb.z, acc[mi][3] + bb.w};
      uint32_t mk4[4];
#pragma unroll
      for (int ni = 0; ni < 4; ni++) {
        float c = c4[ni];
        float v = 0.0f;
        int p = 0;
#pragma unroll 1
        for (int s = 1; s <= T_SIM; s++) {
          float h1 = v + c;                   // f32 add, as reference
          if (h1 >= 1.0f) { p = s; break; }
          v = h1;
        }
        uint32_t mk = 0;
        if (p) for (int s = p; s <= T_SIM; s += p) mk |= 1u << (s - 1);
        mk4[ni] = mk;
      }
      *(uint4*)&mb[(size_t)m * H_DIM + hOut] =
          make_uint4(mk4[0], mk4[1], mk4[2], mk4[3]);
    }
  }
}

// ---------------------------------------------------------------------------
// K2: SNN scan — R6 version verbatim (proven ~125 us; R8's global w-gather
// regressed to ~185: W2GT exactly fills L1 and the LDS->VMEM dependent
// chain went latency-serial).  40 KB LDS -> 4 blocks/CU, 20 waves.
// ---------------------------------------------------------------------------
__global__ __launch_bounds__(320) void snn_scan(const uint32_t* __restrict__ mb,
                                                const float* __restrict__ W2,
                                                const float* __restrict__ b2,
                                                float* __restrict__ out) {
  __shared__ __align__(16) float W2T[H_DIM * D_OUT];  // [h][o], 32000 B
  __shared__ __align__(16) uint2 pkS[2][CAP];         // {h*40, mask}, 7168 B
  __shared__ int   lenS[2];
  __shared__ float b2f[D_OUT];
  float* c2s = (float*)&pkS[0][0];            // union: [r][t][o], 2560 B
  const int tid  = threadIdx.x;               // 0..319
  const int row0 = blockIdx.x * 2;

  if (tid < D_OUT) b2f[tid] = b2[tid];

  if (tid < 128) {
    // ---- Build (waves 0-1): ballot-compact mask words, ascending h ----
    const int r = tid >> 6, ln = tid & 63;
    const uint64_t lm = (1ull << ln) - 1ull;
    const uint32_t* mrow = mb + (size_t)(row0 + r) * H_DIM;
    uint32_t mv[13];
#pragma unroll
    for (int ch = 0; ch < 13; ++ch) {         // independent coalesced loads
      int h = ch * 64 + ln;
      mv[ch] = (h < H_DIM) ? mrow[h] : 0u;
    }
    int off = 0;
#pragma unroll
    for (int ch = 0; ch < 13; ++ch) {
      bool g = (mv[ch] != 0u);
      uint64_t bal = __ballot(g);
      int pos = off + __popcll(bal & lm);
      if (g && pos < CAP) {
        uint2 pk; pk.x = (uint32_t)((ch * 64 + ln) * 40); pk.y = mv[ch];
        pkS[r][pos] = pk;
      }
      off += __popcll(bal);
    }
    if (off <= CAP) {                         // self-pad to multiple of 64
      int lp = (off + 63) & ~63;              // <= CAP since off <= CAP
      int i = off + ln;
      if (i < lp) { pkS[r][i].x = 0u; pkS[r][i].y = 0u; }
    }
    if (ln == 0) lenS[r] = off;
  } else {
    // ---- W2T staging (waves 2-4): coalesced read, LDS scatter ----
    for (int e = tid - 128; e < H_DIM * D_OUT; e += 192) {
      int o = e / H_DIM, h = e - o * H_DIM;
      W2T[h * D_OUT + o] = W2[e];
    }
  }
  __syncthreads();

  // ---- Exec: wave j = o-pair, lanes (t, r); 2 LDS ops per entry ----
  float s0 = 0.0f, s1 = 0.0f;
  const int j = tid >> 6;                     // 0..4
  const int lane = tid & 63;
  const int t = lane & 31;
  const int r = lane >> 5;
  const bool ovf = (lenS[0] > CAP) || (lenS[1] > CAP);
  {
    if (!ovf) {
      const int Lpad = (lenS[r] + 63) & ~63;  // per-r trip count (divergent ok)
      const uint2* pp = pkS[r];
      const char* wbase = (const char*)W2T + 8 * j;
#pragma unroll 8
      for (int i = 0; i < Lpad; ++i) {
        uint2 pk = pp[i];                     // b64, 2-distinct broadcast
        float2 w = *(const float2*)(wbase + pk.x);  // b64, 2-distinct
        bool g = (pk.y >> t) & 1u;
        s0 += g ? w.x : 0.0f;                 // identical op to ref (+w / +0)
        s1 += g ? w.y : 0.0f;
      }
    } else {                                  // overflow fallback: gated scan
      const uint32_t* mrow = mb + (size_t)(row0 + r) * H_DIM;
      const uint32_t vbit = 1u << t;
      for (int h = 0; h < H_DIM; ++h) {
        uint32_t mk = mrow[h];
        float2 w = *(const float2*)&W2T[h * D_OUT + 2 * j];
        s0 += (mk & vbit) ? w.x : 0.0f;
        s1 += (mk & vbit) ? w.y : 0.0f;
      }
    }
  }
  __syncthreads();                            // all pk reads complete
  c2s[((r * T_SIM) + t) * D_OUT + 2 * j]     = s0;   // union region write
  c2s[((r * T_SIM) + t) * D_OUT + 2 * j + 1] = s1;
  __syncthreads();

  // ---- Layer-2 IF scan + spike count (exact f32 ref order) ----
  if (tid < 2 * D_OUT) {
    const int rr = tid / D_OUT, o = tid % D_OUT;
    const float bb = b2f[o];
    float v = 0.0f; int cnt = 0;
#pragma unroll
    for (int tt = 0; tt < T_SIM; ++tt) {
      float cur2 = c2s[((rr * T_SIM) + tt) * D_OUT + o] + bb;  // f32 add
      float h2 = v + cur2;                    // f32 add
      bool spk = (h2 >= 1.0f);
      cnt += spk ? 1 : 0;
      v = spk ? 0.0f : h2;
    }
    out[(size_t)(row0 + rr) * D_OUT + o] = (float)cnt;
  }
}

// ---------------------------------------------------------------------------
extern "C" void kernel_launch(void* const* d_in, const int* in_sizes, int n_in,
                              void* d_out, int out_size, void* d_ws, size_t ws_size,
                              hipStream_t stream) {
  const float* x  = (const float*)d_in[0];
  const float* W1 = (const float*)d_in[1];
  const float* b1 = (const float*)d_in[2];
  const float* W2 = (const float*)d_in[3];
  const float* b2 = (const float*)d_in[4];
  float* outp = (float*)d_out;

  // workspace layout (16B-aligned sections):
  float*    W1T  = (float*)d_ws;                               // 2,508,800 B
  uint32_t* mbuf = (uint32_t*)((char*)d_ws + 2508800);         // 13,107,200 B
  uint8_t*  xf8  = (uint8_t*)((char*)d_ws + 2508800 + 13107200); // 3,211,264 B

  gen_xfixed8<<<dim3(16, 49), 256, 0, stream>>>(x, xf8);
  transpose_w1<<<(D_IN * H_DIM + 255) / 256, 256, 0, stream>>>(W1, W1T);

  dim3 g1(13, 64);                                  // 13 x 64 = 832 blocks
  gemm_masks<<<g1, 256, 0, stream>>>(xf8, W1T, b1, mbuf);

  snn_scan<<<B_ROWS / 2, 320, 0, stream>>>(mbuf, W2, b2, outp);
}

// Round 10
// 275.825 us; speedup vs baseline: 1.4113x; 1.0630x over previous
//
#include <hip/hip_runtime.h>
#include <stdint.h>

// Problem constants (fixed by setup_inputs; all tensors f32)
#define B_ROWS 4096
#define D_IN   784
#define H_DIM  800
#define D_OUT  10
#define T_SIM  32
#define N_ELEM (B_ROWS * D_IN)   // 3211264
#define CAP    448               // spiking-list cap/row (mean ~376, sd ~14)

// ---------------------------------------------------------------------------
// Bit-exact JAX threefry2x32 (key = PRNGKey(42) = {0, 42})
// ---------------------------------------------------------------------------
__device__ __forceinline__ void threefry2x32(uint32_t k0, uint32_t k1,
                                             uint32_t& x0, uint32_t& x1) {
  uint32_t ks0 = k0, ks1 = k1, ks2 = k0 ^ k1 ^ 0x1BD11BDAu;
  x0 += ks0; x1 += ks1;
#define TF_RND(r) { x0 += x1; x1 = (x1 << (r)) | (x1 >> (32 - (r))); x1 ^= x0; }
  TF_RND(13) TF_RND(15) TF_RND(26) TF_RND(6)
  x0 += ks1; x1 += ks2 + 1u;
  TF_RND(17) TF_RND(29) TF_RND(16) TF_RND(24)
  x0 += ks2; x1 += ks0 + 2u;
  TF_RND(13) TF_RND(15) TF_RND(26) TF_RND(6)
  x0 += ks0; x1 += ks1 + 3u;
  TF_RND(17) TF_RND(29) TF_RND(16) TF_RND(24)
  x0 += ks1; x1 += ks2 + 4u;
  TF_RND(13) TF_RND(15) TF_RND(26) TF_RND(6)
  x0 += ks2; x1 += ks0 + 5u;
#undef TF_RND
}

// ---------------------------------------------------------------------------
// K0a: x_fixed computed DIRECTLY in transposed layout xfT[k][m] (k-major).
// Same threefry counter i = m*784 + k -> bit-identical values.
// ---------------------------------------------------------------------------
__global__ __launch_bounds__(256) void gen_xfixed_T(const float* __restrict__ x,
                                                    float* __restrict__ xfT) {
  const int m = blockIdx.x * 256 + threadIdx.x;   // 0..4095
  const int kb = blockIdx.y * 16;                 // 0,16,..,768
#pragma unroll 1
  for (int kk = 0; kk < 16; ++kk) {
    const int k = kb + kk;
    const int i = m * D_IN + k;
    uint32_t c0 = 0u, c1 = (uint32_t)i;
    threefry2x32(0u, 42u, c0, c1);
    uint32_t bits = c0 ^ c1;
    float u = __uint_as_float((bits >> 9) | 0x3F800000u) - 1.0f;
    xfT[(size_t)k * B_ROWS + m] = (u < x[i]) ? 1.0f : 0.0f;
  }
}

// K0b: W1T[k][h] = W1[h][k] — bit-exact copy, 2.5 MB. Coalesced writes.
__global__ __launch_bounds__(256) void transpose_w1(const float* __restrict__ W1,
                                                    float* __restrict__ W1T) {
  const int idx = blockIdx.x * 256 + threadIdx.x;   // over k*800+h
  if (idx >= D_IN * H_DIM) return;
  const int k = idx / H_DIM;
  const int h = idx - k * H_DIM;
  W1T[idx] = W1[h * D_IN + k];
}

// ---------------------------------------------------------------------------
// K1: R6 VERBATIM (measured 144.5 us — best of 6 structural variants).
// Evidence: R7 (hand vmcnt) 186, R8 (BM=128) 186, R9 (u8 A) 156.5 — the
// kernel is issue/latency-bound, not LDS-BW-bound; compiler schedule at
// this structure wins.  64x64/4x4, async global_load_lds width-16 from
// k-major xfT/W1T, LDS double-buffer, ONE __syncthreads per tile.
// Exactness: per output single f32 acc, strict ascending-k fma chain,
// identical epilogue -> bit-identical (absmax 0.0).
// ---------------------------------------------------------------------------
#define BK 16

#define GL2LDS(g, l) __builtin_amdgcn_global_load_lds(                      \
    (const __attribute__((address_space(1))) void*)(g),                     \
    (__attribute__((address_space(3))) void*)(l), 16, 0, 0)

__global__ __launch_bounds__(256) void gemm_masks(const float* __restrict__ xfT,
                                                  const float* __restrict__ W1T,
                                                  const float* __restrict__ b1,
                                                  uint32_t* __restrict__ mb) {
  __shared__ __align__(16) float As[2][BK][64];   // 2 x 4 KB, linear
  __shared__ __align__(16) float Bs[2][BK][64];   // 2 x 4 KB, linear
  const int t  = threadIdx.x;        // 0..255
  const int tx = t & 15, ty = t >> 4;
  const int m0 = blockIdx.y * 64;
  const int n0 = blockIdx.x * 64;

  // staging geometry: wave w stages rows 4w..4w+3 of each 16x64 tile
  const int w = t >> 6;              // wave 0..3
  const int l = t & 63;              // lane
  const int skk = 4 * w + (l >> 4);  // source row 0..15
  const int sm  = (l & 15) * 4;      // source col group
  const float* gA = xfT + (size_t)skk * B_ROWS + m0 + sm;  // + tt*16*4096
  const float* gB = W1T + (size_t)skk * H_DIM + n0 + sm;   // + tt*16*800

#define STAGE(buf, tt) {                                                    \
    GL2LDS(gA + (size_t)(tt) * BK * B_ROWS, &As[buf][4 * w][0]);            \
    GL2LDS(gB + (size_t)(tt) * BK * H_DIM,  &Bs[buf][4 * w][0]); }

  STAGE(0, 0);
  __syncthreads();                       // vmcnt(0) drain -> tile 0 ready

  float acc[4][4] = {};
  const int NT = D_IN / BK;              // 49 tiles, ascending k
#pragma unroll 1
  for (int tt = 0; tt < NT; ++tt) {
    const int cur = tt & 1;
    if (tt + 1 < NT) STAGE(cur ^ 1, tt + 1);   // async into other buffer
#pragma unroll
    for (int kk = 0; kk < BK; kk++) {    // strict ascending k, single acc
      float4 av = *(const float4*)&As[cur][kk][ty * 4];   // ds_read_b128
      float4 bv = *(const float4*)&Bs[cur][kk][tx * 4];   // ds_read_b128
      float a[4] = {av.x, av.y, av.z, av.w};
      float b[4] = {bv.x, bv.y, bv.z, bv.w};
#pragma unroll
      for (int mi = 0; mi < 4; mi++)
#pragma unroll
        for (int ni = 0; ni < 4; ni++)
          acc[mi][ni] = __builtin_fmaf(a[mi], b[ni], acc[mi][ni]);
    }
    __syncthreads();                     // ONE barrier per tile (proven R6)
  }
#undef STAGE

  // Epilogue: + b1 (f32 add like ref), exact f32 IF-period loop, emit mask32
  const int hOut = n0 + tx * 4;          // multiple of 4
  if (hOut < H_DIM) {
    float4 bb = *(const float4*)&b1[hOut];
#pragma unroll
    for (int mi = 0; mi < 4; mi++) {
      int m = m0 + ty * 4 + mi;
      float c4[4] = {acc[mi][0] + bb.x, acc[mi][1] + bb.y,
                     acc[mi][2] + bb.z, acc[mi][3] + bb.w};
      uint32_t mk4[4];
#pragma unroll
      for (int ni = 0; ni < 4; ni++) {
        float c = c4[ni];
        float v = 0.0f;
        int p = 0;
#pragma unroll 1
        for (int s = 1; s <= T_SIM; s++) {
          float h1 = v + c;                   // f32 add, as reference
          if (h1 >= 1.0f) { p = s; break; }
          v = h1;
        }
        uint32_t mk = 0;
        if (p) for (int s = p; s <= T_SIM; s += p) mk |= 1u << (s - 1);
        mk4[ni] = mk;
      }
      *(uint4*)&mb[(size_t)m * H_DIM + hOut] =
          make_uint4(mk4[0], mk4[1], mk4[2], mk4[3]);
    }
  }
}

// ---------------------------------------------------------------------------
// K2 (R10): same proven exec loop as R6, but 4 ROWS PER BLOCK (640 threads).
// K2 model: exec = ~97 us/CU of LDS demand; R6 measured ~125 at 20 waves/CU
// (78% util) -> partially latency-bound.  W2T (32 KB) amortized over 4 rows:
// LDS = 32000 + pkS[4][448]*8 (14336) + small ~= 46.4 KB -> 3 blocks/CU
// x 10 waves = 30 waves/CU (+50% hiding); W2T stage traffic per row halves.
// Wave j (0..9): o-pair j%5, row-pair (j/5)*2 + lane-half.  The per-
// (row,t,o) ascending-h single-accumulator gated fold, pads (mask=0),
// and overflow fallback are IDENTICAL to R6 -> bit-exact.
// ---------------------------------------------------------------------------
__global__ __launch_bounds__(640) void snn_scan(const uint32_t* __restrict__ mb,
                                                const float* __restrict__ W2,
                                                const float* __restrict__ b2,
                                                float* __restrict__ out) {
  __shared__ __align__(16) float W2T[H_DIM * D_OUT];  // [h][o], 32000 B
  __shared__ __align__(16) uint2 pkS[4][CAP];         // {h*40, mask}, 14336 B
  __shared__ int   lenS[4];
  __shared__ float b2f[D_OUT];
  float* c2s = (float*)&pkS[0][0];            // union: [rr][t][o], 5120 B
  const int tid  = threadIdx.x;               // 0..639
  const int row0 = blockIdx.x * 4;

  if (tid < D_OUT) b2f[tid] = b2[tid];

  if (tid < 256) {
    // ---- Build (waves 0-3): ballot-compact mask words, ascending h ----
    const int r = tid >> 6, ln = tid & 63;    // r = row 0..3
    const uint64_t lm = (1ull << ln) - 1ull;
    const uint32_t* mrow = mb + (size_t)(row0 + r) * H_DIM;
    uint32_t mv[13];
#pragma unroll
    for (int ch = 0; ch < 13; ++ch) {         // independent coalesced loads
      int h = ch * 64 + ln;
      mv[ch] = (h < H_DIM) ? mrow[h] : 0u;
    }
    int off = 0;
#pragma unroll
    for (int ch = 0; ch < 13; ++ch) {
      bool g = (mv[ch] != 0u);
      uint64_t bal = __ballot(g);
      int pos = off + __popcll(bal & lm);
      if (g && pos < CAP) {
        uint2 pk; pk.x = (uint32_t)((ch * 64 + ln) * 40); pk.y = mv[ch];
        pkS[r][pos] = pk;
      }
      off += __popcll(bal);
    }
    if (off <= CAP) {                         // self-pad to multiple of 64
      int lp = (off + 63) & ~63;              // <= CAP since off <= CAP
      int i = off + ln;
      if (i < lp) { pkS[r][i].x = 0u; pkS[r][i].y = 0u; }
    }
    if (ln == 0) lenS[r] = off;
  } else {
    // ---- W2T staging (waves 4-9): coalesced read, LDS scatter ----
    for (int e = tid - 256; e < H_DIM * D_OUT; e += 384) {
      int o = e / H_DIM, h = e - o * H_DIM;
      W2T[h * D_OUT + o] = W2[e];
    }
  }
  __syncthreads();

  // ---- Exec: wave j: o-pair j%5, rows (j/5)*2 + lane-half ----
  float s0 = 0.0f, s1 = 0.0f;
  const int j  = tid >> 6;                    // 0..9
  const int jp = j % 5;                       // o-pair
  const int lane = tid & 63;
  const int t  = lane & 31;
  const int rr = (j / 5) * 2 + (lane >> 5);   // row 0..3
  const bool ovf = (lenS[0] > CAP) || (lenS[1] > CAP) ||
                   (lenS[2] > CAP) || (lenS[3] > CAP);
  {
    if (!ovf) {
      const int Lpad = (lenS[rr] + 63) & ~63; // per-row trip count
      const uint2* pp = pkS[rr];
      const char* wbase = (const char*)W2T + 8 * jp;
#pragma unroll 8
      for (int i = 0; i < Lpad; ++i) {
        uint2 pk = pp[i];                     // b64, 2-distinct broadcast
        float2 w = *(const float2*)(wbase + pk.x);  // b64, 2-distinct
        bool g = (pk.y >> t) & 1u;
        s0 += g ? w.x : 0.0f;                 // identical op to ref (+w / +0)
        s1 += g ? w.y : 0.0f;
      }
    } else {                                  // overflow fallback: gated scan
      const uint32_t* mrow = mb + (size_t)(row0 + rr) * H_DIM;
      const uint32_t vbit = 1u << t;
      const char* wbase = (const char*)W2T + 8 * jp;
      for (int h = 0; h < H_DIM; ++h) {
        uint32_t mk = mrow[h];
        float2 w = *(const float2*)(wbase + h * 40);
        s0 += (mk & vbit) ? w.x : 0.0f;
        s1 += (mk & vbit) ? w.y : 0.0f;
      }
    }
  }
  __syncthreads();                            // all pk reads complete
  c2s[((rr * T_SIM) + t) * D_OUT + 2 * jp]     = s0;   // union region write
  c2s[((rr * T_SIM) + t) * D_OUT + 2 * jp + 1] = s1;
  __syncthreads();

  // ---- Layer-2 IF scan + spike count (exact f32 ref order) ----
  if (tid < 4 * D_OUT) {
    const int rw = tid / D_OUT, o = tid % D_OUT;
    const float bb = b2f[o];
    float v = 0.0f; int cnt = 0;
#pragma unroll
    for (int tt = 0; tt < T_SIM; ++tt) {
      float cur2 = c2s[((rw * T_SIM) + tt) * D_OUT + o] + bb;  // f32 add
      float h2 = v + cur2;                    // f32 add
      bool spk = (h2 >= 1.0f);
      cnt += spk ? 1 : 0;
      v = spk ? 0.0f : h2;
    }
    out[(size_t)(row0 + rw) * D_OUT + o] = (float)cnt;
  }
}

// ---------------------------------------------------------------------------
extern "C" void kernel_launch(void* const* d_in, const int* in_sizes, int n_in,
                              void* d_out, int out_size, void* d_ws, size_t ws_size,
                              hipStream_t stream) {
  const float* x  = (const float*)d_in[0];
  const float* W1 = (const float*)d_in[1];
  const float* b1 = (const float*)d_in[2];
  const float* W2 = (const float*)d_in[3];
  const float* b2 = (const float*)d_in[4];
  float* outp = (float*)d_out;

  float*    xfT  = (float*)d_ws;                    // 784*4096 f32 (12.85 MB)
  float*    W1T  = xfT + (size_t)D_IN * B_ROWS;     // 784*800  f32 ( 2.51 MB)
  uint32_t* mbuf = (uint32_t*)(W1T + (size_t)D_IN * H_DIM);  // B*H u32 (13.1 MB)

  gen_xfixed_T<<<dim3(16, 49), 256, 0, stream>>>(x, xfT);
  transpose_w1<<<(D_IN * H_DIM + 255) / 256, 256, 0, stream>>>(W1, W1T);

  dim3 g1(13, 64);                                  // 13 x 64 = 832 blocks
  gemm_masks<<<g1, 256, 0, stream>>>(xfT, W1T, b1, mbuf);

  snn_scan<<<B_ROWS / 4, 640, 0, stream>>>(mbuf, W2, b2, outp);
}